// Round 1
// baseline (315.136 us; speedup 1.0000x reference)
//
#include <hip/hip_runtime.h>
#include <hip/hip_fp16.h>

// GMM (MoNet) graph conv, 2 layers. Commuted-GEMM: h[n] = (sum_e g[e,k] x[col e]) . W1.
// R13 -> R14: L2-resident feature-sliced gather. xh/hh stored SLICE-MAJOR (16 feats = 3.2MB
// per slice < 4MiB/XCD L2). Each layer does NSLICE sequential in-kernel passes; ~all blocks
// co-resident (128 nodes/block -> 782 blocks, 3/CU) so the device phase-aligns on one slice
// at a time and the 16x row reuse becomes L2 hits instead of Infinity-Cache fabric traffic
// (prior ceiling: ~5.5 TB/s effective on random 128B lines). col/gauss hoisted to registers
// ONCE per node and reused across passes (redundancy x8 -> x2).

#define KK 3

using half8   = __attribute__((ext_vector_type(8))) _Float16;
using float4v = __attribute__((ext_vector_type(4))) float;

// gauss (fp16 half4 per edge), x fp32->fp16 slice-major, W1/W2 -> MFMA B-fragment order.
__global__ void setup_kernel(const float* __restrict__ p, const float* __restrict__ mu,
                             const float* __restrict__ sigma, float2* __restrict__ gaussh,
                             const float* __restrict__ x, __half* __restrict__ xh,
                             const float* __restrict__ W1, const float* __restrict__ W2,
                             __half* __restrict__ B1, __half* __restrict__ B2,
                             int E, int NX8, int NN) {
    int t = blockIdx.x * blockDim.x + threadIdx.x;
    if (t < E) {
        float p0 = p[2 * t], p1 = p[2 * t + 1];
        float g[KK];
#pragma unroll
        for (int k = 0; k < KK; ++k) {
            float m0 = mu[2 * k], m1 = mu[2 * k + 1];
            float s0 = sigma[2 * k], s1 = sigma[2 * k + 1];
            float d0 = p0 - m0, d1 = p1 - m1;
            float q = (d0 * d0) / (s0 * s0) + (d1 * d1) / (s1 * s1);
            g[k] = __expf(-0.5f * q);
        }
        union { __half h[4]; float2 v; } o;
        o.h[0] = __float2half(g[0]); o.h[1] = __float2half(g[1]);
        o.h[2] = __float2half(g[2]); o.h[3] = __float2half(0.f);
        gaussh[t] = o.v;
    }
    if (t < NX8) {
        int nn = t >> 3, c = t & 7;              // chunk c = feats [c*8, c*8+8)
        float4 v0 = ((const float4*)x)[2 * t];
        float4 v1 = ((const float4*)x)[2 * t + 1];
        union { __half h[8]; float4 v; } o;
        o.h[0] = __float2half(v0.x); o.h[1] = __float2half(v0.y);
        o.h[2] = __float2half(v0.z); o.h[3] = __float2half(v0.w);
        o.h[4] = __float2half(v1.x); o.h[5] = __float2half(v1.y);
        o.h[6] = __float2half(v1.z); o.h[7] = __float2half(v1.w);
        // slice-major: slice (c>>1) holds feats [(c>>1)*16, +16) of all nodes contiguously
        ((float4*)xh)[((size_t)(c >> 1) * NN + nn) * 2 + (c & 1)] = o.v;
    }
    if (t < 6144) {                    // W1: J=192 (KB=6), H=32 (OT=2)
        int j = t & 7, lane = (t >> 3) & 63, grp = t >> 9;   // grp = ot*6+kb
        int ot = grp / 6, kb = grp % 6;
        int kidx = kb * 32 + (lane >> 4) * 8 + j;
        B1[t] = __float2half(W1[kidx * 32 + ot * 16 + (lane & 15)]);
    } else if (t < 6144 + 1536) {      // W2: J=96 (KB=3), H=16 (OT=1)
        int t2 = t - 6144;
        int j = t2 & 7, lane = (t2 >> 3) & 63, kb = t2 >> 9;
        int kidx = kb * 32 + (lane >> 4) * 8 + j;
        B2[t2] = __float2half(W2[kidx * 16 + (lane & 15)]);
    }
}

__device__ __forceinline__ void unpack8(float4 raw, float* f) {
    union { float4 v; __half2 h2[4]; } u;
    u.v = raw;
#pragma unroll
    for (int q = 0; q < 4; ++q) {
        float2 t = __half22float2(u.h2[q]);
        f[2 * q] = t.x; f[2 * q + 1] = t.y;
    }
}

__device__ __forceinline__ void fma_edge_u(float4 xr, unsigned long long graw,
                                           float* a0, float* a1, float* a2) {
    union { unsigned long long u; __half2 h2[2]; } ug; ug.u = graw;
    float2 gab = __half22float2(ug.h2[0]);
    float2 gc_ = __half22float2(ug.h2[1]);
    float f[8];
    unpack8(xr, f);
#pragma unroll
    for (int q = 0; q < 8; ++q) {
        a0[q] = fmaf(gab.x, f[q], a0[q]);
        a1[q] = fmaf(gab.y, f[q], a1[q]);
        a2[q] = fmaf(gc_.x, f[q], a2[q]);
    }
}

// Phase 1 (gather): NSLICE sequential passes over 3.2MB feature slices (L2-resident).
// thread = (node nl, 8-feature half-of-slice ch); col/gauss in regs across passes.
// Phase 2 (MFMA): wave-task loop over (16-node tile, output tile); A from LDS, B pre-packed.
template <int F, int H, bool OUT_HALF>
__global__ __launch_bounds__(256, 3) void fused_layer(
    const int* __restrict__ row_ptr, const int* __restrict__ col_idx,
    const float2* __restrict__ gaussh, const __half* __restrict__ xh,
    const __half* __restrict__ Bpack, void* __restrict__ yout, int N) {
    constexpr int NSLICE = F / 16;           // 4 / 2
    constexpr int NODES  = 128;
    constexpr int J      = KK * F;           // 192 / 96
    constexpr int STRIDE = (F == 64) ? 200 : 104;  // halves (bank-stagger pad)
    constexpr int KB     = J / 32;           // 6 / 3
    constexpr int OT     = H / 16;           // 2 / 1

    __shared__ __align__(16) __half sLh[NODES * STRIDE];

    const int tid = threadIdx.x;
    const int nl  = tid >> 1;                // node within block
    const int ch  = tid & 1;                 // 8-feat half of the 16-feat slice
    const int n   = blockIdx.x * NODES + nl;

    // hoist col + gauss for the full deg-16 batch ONCE (reused across all passes)
    int cols[16];
    unsigned long long gr[16];
    int e0 = 0, e1 = 0;
#pragma unroll
    for (int j = 0; j < 16; ++j) { cols[j] = 0; gr[j] = 0ull; }
    if (n < N) {
        e0 = row_ptr[n]; e1 = row_ptr[n + 1];
        int cnt = e1 - e0;
        int cl = cnt > 16 ? 16 : cnt;
        if (cnt > 0) {
#pragma unroll
            for (int j = 0; j < 16; ++j) {
                int idx = e0 + (j < cl ? j : cl - 1);
                cols[j] = col_idx[idx];
            }
#pragma unroll
            for (int j = 0; j < 16; ++j) {
                int idx = e0 + (j < cl ? j : cl - 1);
                unsigned long long g = ((const unsigned long long*)gaussh)[idx];
                gr[j] = (j < cl) ? g : 0ull;
            }
        }
    }

#pragma unroll 1
    for (int p = 0; p < NSLICE; ++p) {
        const float4* xs = (const float4*)xh + (size_t)p * N * 2;   // 3.2MB slice base
        float a0[8], a1[8], a2[8];
#pragma unroll
        for (int q = 0; q < 8; ++q) { a0[q] = 0.f; a1[q] = 0.f; a2[q] = 0.f; }

        float4 xrA[8], xrB[8];
#pragma unroll
        for (int j = 0; j < 8; ++j) xrA[j] = xs[(size_t)cols[j] * 2 + ch];
#pragma unroll
        for (int j = 0; j < 8; ++j) xrB[j] = xs[(size_t)cols[8 + j] * 2 + ch];
#pragma unroll
        for (int j = 0; j < 8; ++j) fma_edge_u(xrA[j], gr[j], a0, a1, a2);
#pragma unroll
        for (int j = 0; j < 8; ++j) fma_edge_u(xrB[j], gr[8 + j], a0, a1, a2);
        for (int e = e0 + 16; e < e1; ++e) {        // deg>16 fallback (not hit here)
            int c = col_idx[e];
            unsigned long long g = ((const unsigned long long*)gaussh)[e];
            fma_edge_u(xs[(size_t)c * 2 + ch], g, a0, a1, a2);
        }

        // dump this pass's 16-feat slice of the s-tile to LDS (fp16)
        union { __half h[8]; half8 v; } o;
#pragma unroll
        for (int q = 0; q < 8; ++q) o.h[q] = __float2half(a0[q]);
        *(half8*)(sLh + nl * STRIDE + 0 * F + p * 16 + ch * 8) = o.v;
#pragma unroll
        for (int q = 0; q < 8; ++q) o.h[q] = __float2half(a1[q]);
        *(half8*)(sLh + nl * STRIDE + 1 * F + p * 16 + ch * 8) = o.v;
#pragma unroll
        for (int q = 0; q < 8; ++q) o.h[q] = __float2half(a2[q]);
        *(half8*)(sLh + nl * STRIDE + 2 * F + p * 16 + ch * 8) = o.v;
    }
    __syncthreads();

    // phase 2: 4 waves x wave-task loop over (node-tile, output-tile)
    {
        const int wv   = tid >> 6;
        const int lane = tid & 63;
        const int quad = lane >> 4;
        const int m    = lane & 15;
        const int ot   = (OT == 2) ? (wv & 1) : 0;
        const int t0   = (OT == 2) ? (wv >> 1) : wv;
        constexpr int TSTEP = (OT == 2) ? 2 : 4;

        half8 b[KB];
#pragma unroll
        for (int kb = 0; kb < KB; ++kb)
            b[kb] = ((const half8*)Bpack)[(ot * KB + kb) * 64 + lane];

#pragma unroll 1
        for (int t = t0; t < NODES / 16; t += TSTEP) {
            const int n0 = blockIdx.x * NODES + t * 16;
            if (n0 >= N) break;
            const half8* av = (const half8*)(sLh + (size_t)(t * 16 + m) * STRIDE);
            float4v acc = {0.f, 0.f, 0.f, 0.f};
#pragma unroll
            for (int kb = 0; kb < KB; ++kb)
                acc = __builtin_amdgcn_mfma_f32_16x16x32_f16(av[kb * 4 + quad], b[kb], acc, 0, 0, 0);

            // C/D: col = lane&15 (output), row = quad*4+reg (node)
#pragma unroll
            for (int reg = 0; reg < 4; ++reg) {
                int nn = n0 + quad * 4 + reg;
                if (nn < N) {
                    if constexpr (OUT_HALF)   // slice-major fp16 for the next layer's gather
                        ((__half*)yout)[((size_t)ot * N + nn) * 16 + m] = __float2half(acc[reg]);
                    else
                        ((float*)yout)[(size_t)nn * H + m] = acc[reg];
                }
            }
        }
    }
}

extern "C" void kernel_launch(void* const* d_in, const int* in_sizes, int n_in,
                              void* d_out, int out_size, void* d_ws, size_t ws_size,
                              hipStream_t stream) {
    const int* row_ptr  = (const int*)d_in[0];
    const int* col_idx  = (const int*)d_in[1];
    const float* x      = (const float*)d_in[2];
    const float* p      = (const float*)d_in[3];
    const float* mu     = (const float*)d_in[4];
    const float* sigma  = (const float*)d_in[5];
    const float* W1     = (const float*)d_in[6];
    const float* W2     = (const float*)d_in[7];

    const int N = in_sizes[0] - 1;
    const int E = in_sizes[1];

    float2* gaussh = (float2*)d_ws;                  // E * 8 B
    __half* B1pack = (__half*)(gaussh + (size_t)E);  // 6144 halves
    __half* B2pack = B1pack + 6144;                  // 1536 halves
    __half* xh     = B2pack + 1536;                  // N*64 fp16, slice-major (4 x 3.2MB)
    __half* hh     = xh + (size_t)N * 64;            // N*32 fp16, slice-major (2 x 3.2MB)
    float*  out    = (float*)d_out;                  // N*16 f32

    const int B = 256;
    const int NX8 = N * 8;
    int setup_n = E > NX8 ? E : NX8;
    if (setup_n < 7680) setup_n = 7680;

    setup_kernel<<<(setup_n + B - 1) / B, B, 0, stream>>>(
        p, mu, sigma, gaussh, x, xh, W1, W2, B1pack, B2pack, E, NX8, N);

    fused_layer<64, 32, true><<<(N + 127) / 128, B, 0, stream>>>(
        row_ptr, col_idx, gaussh, xh, B1pack, (void*)hh, N);
    fused_layer<32, 16, false><<<(N + 127) / 128, B, 0, stream>>>(
        row_ptr, col_idx, gaussh, hh, B2pack, (void*)out, N);
}

// Round 3
// 160.449 us; speedup vs baseline: 1.9641x; 1.9641x over previous
//
#include <hip/hip_runtime.h>
#include <hip/hip_fp16.h>

// GMM (MoNet) graph conv, 2 layers. Commuted-GEMM: h[n] = (sum_e g[e,k] x[col e]) . W1.
// R15 -> R15b: fix nontemporal builtin compile error (HIP float2/float4 are structs ->
// use native ext_vector/integer types for nt loads). Structure identical to R13 (153.5us)
// + nt hints on pure streams (col_idx, gaussh loads; final out stores; setup p/x reads)
// so streaming traffic stops evicting the gather arrays (xh 12.8MB / hh 6.4MB) from the
// 4MiB per-XCD L2s. hh stores stay cached (re-read by layer 2).

#define KK 3

using half8   = __attribute__((ext_vector_type(8))) _Float16;
using float4v = __attribute__((ext_vector_type(4))) float;
using float2v = __attribute__((ext_vector_type(2))) float;

// gauss (fp16 half4 per edge), x fp32->fp16, W1/W2 -> MFMA B-fragment order (fp16).
__global__ void setup_kernel(const float* __restrict__ p, const float* __restrict__ mu,
                             const float* __restrict__ sigma, float2* __restrict__ gaussh,
                             const float* __restrict__ x, __half* __restrict__ xh,
                             const float* __restrict__ W1, const float* __restrict__ W2,
                             __half* __restrict__ B1, __half* __restrict__ B2,
                             int E, int NX8) {
    int t = blockIdx.x * blockDim.x + threadIdx.x;
    if (t < E) {
        float2v pv = __builtin_nontemporal_load((const float2v*)p + t);
        float p0 = pv.x, p1 = pv.y;
        float g[KK];
#pragma unroll
        for (int k = 0; k < KK; ++k) {
            float m0 = mu[2 * k], m1 = mu[2 * k + 1];
            float s0 = sigma[2 * k], s1 = sigma[2 * k + 1];
            float d0 = p0 - m0, d1 = p1 - m1;
            float q = (d0 * d0) / (s0 * s0) + (d1 * d1) / (s1 * s1);
            g[k] = __expf(-0.5f * q);
        }
        union { __half h[4]; float2 v; } o;
        o.h[0] = __float2half(g[0]); o.h[1] = __float2half(g[1]);
        o.h[2] = __float2half(g[2]); o.h[3] = __float2half(0.f);
        gaussh[t] = o.v;
    }
    if (t < NX8) {
        float4v v0 = __builtin_nontemporal_load((const float4v*)x + 2 * t);
        float4v v1 = __builtin_nontemporal_load((const float4v*)x + 2 * t + 1);
        union { __half h[8]; float4 v; } o;
        o.h[0] = __float2half(v0.x); o.h[1] = __float2half(v0.y);
        o.h[2] = __float2half(v0.z); o.h[3] = __float2half(v0.w);
        o.h[4] = __float2half(v1.x); o.h[5] = __float2half(v1.y);
        o.h[6] = __float2half(v1.z); o.h[7] = __float2half(v1.w);
        ((float4*)xh)[t] = o.v;
    }
    if (t < 6144) {                    // W1: J=192 (KB=6), H=32 (OT=2)
        int j = t & 7, lane = (t >> 3) & 63, grp = t >> 9;   // grp = ot*6+kb
        int ot = grp / 6, kb = grp % 6;
        int kidx = kb * 32 + (lane >> 4) * 8 + j;
        B1[t] = __float2half(W1[kidx * 32 + ot * 16 + (lane & 15)]);
    } else if (t < 6144 + 1536) {      // W2: J=96 (KB=3), H=16 (OT=1)
        int t2 = t - 6144;
        int j = t2 & 7, lane = (t2 >> 3) & 63, kb = t2 >> 9;
        int kidx = kb * 32 + (lane >> 4) * 8 + j;
        B2[t2] = __float2half(W2[kidx * 16 + (lane & 15)]);
    }
}

__device__ __forceinline__ void unpack8(float4 raw, float* f) {
    union { float4 v; __half2 h2[4]; } u;
    u.v = raw;
#pragma unroll
    for (int q = 0; q < 4; ++q) {
        float2 t = __half22float2(u.h2[q]);
        f[2 * q] = t.x; f[2 * q + 1] = t.y;
    }
}

__device__ __forceinline__ void fma_edge_u(float4 xr, unsigned long long graw,
                                           float* a0, float* a1, float* a2) {
    union { unsigned long long u; __half2 h2[2]; } ug; ug.u = graw;
    float2 gab = __half22float2(ug.h2[0]);
    float2 gc_ = __half22float2(ug.h2[1]);
    float f[8];
    unpack8(xr, f);
#pragma unroll
    for (int q = 0; q < 8; ++q) {
        a0[q] = fmaf(gab.x, f[q], a0[q]);
        a1[q] = fmaf(gab.y, f[q], a1[q]);
        a2[q] = fmaf(gc_.x, f[q], a2[q]);
    }
}

// Phase 1 (gather): thread = (node nl, 8-feature chunk ch); fp32 accum; full 16-edge hoist.
// Phase 2 (MFMA): wave = one 16-node x 16-output tile; A from LDS, B pre-packed (L1).
template <int F, int H, bool OUT_HALF>
__global__ __launch_bounds__(256) void fused_layer(
    const int* __restrict__ row_ptr, const int* __restrict__ col_idx,
    const float2* __restrict__ gaussh, const __half* __restrict__ xh,
    const __half* __restrict__ Bpack, void* __restrict__ yout, int N) {
    constexpr int TPN    = F / 8;            // 8 / 4
    constexpr int NODES  = 256 / TPN;        // 32 / 64
    constexpr int J      = KK * F;           // 192 / 96
    constexpr int STRIDE = (F == 64) ? 200 : 104;  // halves
    constexpr int KB     = J / 32;           // 6 / 3
    constexpr int OT     = H / 16;           // 2 / 1

    __shared__ __align__(16) __half sLh[NODES * STRIDE];

    const int tid = threadIdx.x;
    const int nl  = tid / TPN;
    const int ch  = tid % TPN;
    const int n   = blockIdx.x * NODES + nl;

    float a0[8], a1[8], a2[8];
#pragma unroll
    for (int q = 0; q < 8; ++q) { a0[q] = 0.f; a1[q] = 0.f; a2[q] = 0.f; }

    const float4* x4 = (const float4*)xh;
    const unsigned long long* g8 = (const unsigned long long*)gaussh;

    if (n < N) {
        int e0 = row_ptr[n], e1 = row_ptr[n + 1];
        int e = e0;
        for (; e + 16 <= e1; e += 16) {
            int cols[16];
            unsigned long long gr[16];
#pragma unroll
            for (int j = 0; j < 16; ++j) cols[j] = __builtin_nontemporal_load(col_idx + e + j);
#pragma unroll
            for (int j = 0; j < 16; ++j) gr[j] = __builtin_nontemporal_load(g8 + e + j);
            float4 xrA[8], xrB[8];
#pragma unroll
            for (int j = 0; j < 8; ++j) xrA[j] = x4[(size_t)cols[j] * TPN + ch];
#pragma unroll
            for (int j = 0; j < 8; ++j) xrB[j] = x4[(size_t)cols[8 + j] * TPN + ch];
#pragma unroll
            for (int j = 0; j < 8; ++j) fma_edge_u(xrA[j], gr[j], a0, a1, a2);
#pragma unroll
            for (int j = 0; j < 8; ++j) fma_edge_u(xrB[j], gr[8 + j], a0, a1, a2);
        }
        for (; e < e1; ++e) {
            int c = __builtin_nontemporal_load(col_idx + e);
            fma_edge_u(x4[(size_t)c * TPN + ch], __builtin_nontemporal_load(g8 + e),
                       a0, a1, a2);
        }
    }

    // dump s-tile to LDS (fp16)
    {
        union { __half h[8]; half8 v; } o;
#pragma unroll
        for (int q = 0; q < 8; ++q) o.h[q] = __float2half(a0[q]);
        *(half8*)(sLh + nl * STRIDE + 0 * F + ch * 8) = o.v;
#pragma unroll
        for (int q = 0; q < 8; ++q) o.h[q] = __float2half(a1[q]);
        *(half8*)(sLh + nl * STRIDE + 1 * F + ch * 8) = o.v;
#pragma unroll
        for (int q = 0; q < 8; ++q) o.h[q] = __float2half(a2[q]);
        *(half8*)(sLh + nl * STRIDE + 2 * F + ch * 8) = o.v;
    }
    __syncthreads();

    // phase 2: wave -> (node-tile, output-tile)
    {
        const int wv   = tid >> 6;
        const int lane = tid & 63;
        const int tile = wv / OT;
        const int ot   = wv % OT;
        const int n0   = blockIdx.x * NODES + tile * 16;
        if (n0 < N) {
            const int quad = lane >> 4;
            const int m    = lane & 15;

            half8 b[KB];
#pragma unroll
            for (int kb = 0; kb < KB; ++kb)
                b[kb] = ((const half8*)Bpack)[(ot * KB + kb) * 64 + lane];

            const half8* av = (const half8*)(sLh + (size_t)(tile * 16 + m) * STRIDE);
            float4v acc = {0.f, 0.f, 0.f, 0.f};
#pragma unroll
            for (int kb = 0; kb < KB; ++kb)
                acc = __builtin_amdgcn_mfma_f32_16x16x32_f16(av[kb * 4 + quad], b[kb], acc, 0, 0, 0);

            // C/D: col = lane&15 (output), row = quad*4+reg (node)
#pragma unroll
            for (int reg = 0; reg < 4; ++reg) {
                int nn = n0 + quad * 4 + reg;
                if (nn < N) {
                    if constexpr (OUT_HALF) {
                        // hh is re-read by layer 2: keep cached (plain store)
                        ((__half*)yout)[(size_t)nn * H + ot * 16 + m] = __float2half(acc[reg]);
                    } else {
                        // final output: never re-read -> nt store
                        __builtin_nontemporal_store(acc[reg],
                            (float*)yout + (size_t)nn * H + m);
                    }
                }
            }
        }
    }
}

extern "C" void kernel_launch(void* const* d_in, const int* in_sizes, int n_in,
                              void* d_out, int out_size, void* d_ws, size_t ws_size,
                              hipStream_t stream) {
    const int* row_ptr  = (const int*)d_in[0];
    const int* col_idx  = (const int*)d_in[1];
    const float* x      = (const float*)d_in[2];
    const float* p      = (const float*)d_in[3];
    const float* mu     = (const float*)d_in[4];
    const float* sigma  = (const float*)d_in[5];
    const float* W1     = (const float*)d_in[6];
    const float* W2     = (const float*)d_in[7];

    const int N = in_sizes[0] - 1;
    const int E = in_sizes[1];

    float2* gaussh = (float2*)d_ws;                  // E * 8 B
    __half* B1pack = (__half*)(gaussh + (size_t)E);  // 6144 halves
    __half* B2pack = B1pack + 6144;                  // 1536 halves
    __half* xh     = B2pack + 1536;                  // N*64 fp16
    __half* hh     = xh + (size_t)N * 64;            // N*32 fp16
    float*  out    = (float*)d_out;                  // N*16 f32

    const int B = 256;
    const int NX8 = N * 8;
    int setup_n = E > NX8 ? E : NX8;
    if (setup_n < 7680) setup_n = 7680;

    setup_kernel<<<(setup_n + B - 1) / B, B, 0, stream>>>(
        p, mu, sigma, gaussh, x, xh, W1, W2, B1pack, B2pack, E, NX8);

    fused_layer<64, 32, true><<<(N + 31) / 32, B, 0, stream>>>(
        row_ptr, col_idx, gaussh, xh, B1pack, (void*)hh, N);
    fused_layer<32, 16, false><<<(N + 63) / 64, B, 0, stream>>>(
        row_ptr, col_idx, gaussh, hh, B2pack, (void*)out, N);
}

// Round 4
// 154.667 us; speedup vs baseline: 2.0375x; 1.0374x over previous
//
#include <hip/hip_runtime.h>
#include <hip/hip_fp16.h>

// GMM (MoNet) graph conv, 2 layers. Commuted-GEMM: h[n] = (sum_e g[e,k] x[col e]) . W1.
// R15b -> R16: REVERT nt-hint experiment (160.4us vs 153.5: nt demotes gaussh/col lines
// that the *other* layer kernel re-hits in LLC -> net loss). This is the exact R13 kernel
// (verified 153.5us): 3-launch structure, full deg-16 edge-batch hoist in the gather
// (16 col + 16 gauss, then 2x8 payload loads -> 256B in flight/thread), fp16 payloads,
// MFMA epilogue from LDS. Layer-1 gather sits at the session-measured LLC random-128B
// ceiling (~5.5 TB/s); slice-residency (R14) and cache hints (R15b) both regressed.

#define KK 3

using half8   = __attribute__((ext_vector_type(8))) _Float16;
using float4v = __attribute__((ext_vector_type(4))) float;

// gauss (fp16 half4 per edge), x fp32->fp16, W1/W2 -> MFMA B-fragment order (fp16).
__global__ void setup_kernel(const float* __restrict__ p, const float* __restrict__ mu,
                             const float* __restrict__ sigma, float2* __restrict__ gaussh,
                             const float* __restrict__ x, __half* __restrict__ xh,
                             const float* __restrict__ W1, const float* __restrict__ W2,
                             __half* __restrict__ B1, __half* __restrict__ B2,
                             int E, int NX8) {
    int t = blockIdx.x * blockDim.x + threadIdx.x;
    if (t < E) {
        float p0 = p[2 * t], p1 = p[2 * t + 1];
        float g[KK];
#pragma unroll
        for (int k = 0; k < KK; ++k) {
            float m0 = mu[2 * k], m1 = mu[2 * k + 1];
            float s0 = sigma[2 * k], s1 = sigma[2 * k + 1];
            float d0 = p0 - m0, d1 = p1 - m1;
            float q = (d0 * d0) / (s0 * s0) + (d1 * d1) / (s1 * s1);
            g[k] = __expf(-0.5f * q);
        }
        union { __half h[4]; float2 v; } o;
        o.h[0] = __float2half(g[0]); o.h[1] = __float2half(g[1]);
        o.h[2] = __float2half(g[2]); o.h[3] = __float2half(0.f);
        gaussh[t] = o.v;
    }
    if (t < NX8) {
        float4 v0 = ((const float4*)x)[2 * t];
        float4 v1 = ((const float4*)x)[2 * t + 1];
        union { __half h[8]; float4 v; } o;
        o.h[0] = __float2half(v0.x); o.h[1] = __float2half(v0.y);
        o.h[2] = __float2half(v0.z); o.h[3] = __float2half(v0.w);
        o.h[4] = __float2half(v1.x); o.h[5] = __float2half(v1.y);
        o.h[6] = __float2half(v1.z); o.h[7] = __float2half(v1.w);
        ((float4*)xh)[t] = o.v;
    }
    if (t < 6144) {                    // W1: J=192 (KB=6), H=32 (OT=2)
        int j = t & 7, lane = (t >> 3) & 63, grp = t >> 9;   // grp = ot*6+kb
        int ot = grp / 6, kb = grp % 6;
        int kidx = kb * 32 + (lane >> 4) * 8 + j;
        B1[t] = __float2half(W1[kidx * 32 + ot * 16 + (lane & 15)]);
    } else if (t < 6144 + 1536) {      // W2: J=96 (KB=3), H=16 (OT=1)
        int t2 = t - 6144;
        int j = t2 & 7, lane = (t2 >> 3) & 63, kb = t2 >> 9;
        int kidx = kb * 32 + (lane >> 4) * 8 + j;
        B2[t2] = __float2half(W2[kidx * 16 + (lane & 15)]);
    }
}

__device__ __forceinline__ void unpack8(float4 raw, float* f) {
    union { float4 v; __half2 h2[4]; } u;
    u.v = raw;
#pragma unroll
    for (int q = 0; q < 4; ++q) {
        float2 t = __half22float2(u.h2[q]);
        f[2 * q] = t.x; f[2 * q + 1] = t.y;
    }
}

__device__ __forceinline__ void fma_edge(float4 xr, float2 graw,
                                         float* a0, float* a1, float* a2) {
    union { float2 v; __half2 h2[2]; } ug; ug.v = graw;
    float2 gab = __half22float2(ug.h2[0]);
    float2 gc_ = __half22float2(ug.h2[1]);
    float f[8];
    unpack8(xr, f);
#pragma unroll
    for (int q = 0; q < 8; ++q) {
        a0[q] = fmaf(gab.x, f[q], a0[q]);
        a1[q] = fmaf(gab.y, f[q], a1[q]);
        a2[q] = fmaf(gc_.x, f[q], a2[q]);
    }
}

// Phase 1 (gather): thread = (node nl, 8-feature chunk ch); fp32 accum; full 16-edge hoist.
// Phase 2 (MFMA): wave = one 16-node x 16-output tile; A from LDS, B pre-packed (L1).
template <int F, int H, bool OUT_HALF>
__global__ __launch_bounds__(256) void fused_layer(
    const int* __restrict__ row_ptr, const int* __restrict__ col_idx,
    const float2* __restrict__ gaussh, const __half* __restrict__ xh,
    const __half* __restrict__ Bpack, void* __restrict__ yout, int N) {
    constexpr int TPN    = F / 8;            // 8 / 4
    constexpr int NODES  = 256 / TPN;        // 32 / 64
    constexpr int J      = KK * F;           // 192 / 96
    constexpr int STRIDE = (F == 64) ? 200 : 104;  // halves
    constexpr int KB     = J / 32;           // 6 / 3
    constexpr int OT     = H / 16;           // 2 / 1

    __shared__ __align__(16) __half sLh[NODES * STRIDE];

    const int tid = threadIdx.x;
    const int nl  = tid / TPN;
    const int ch  = tid % TPN;
    const int n   = blockIdx.x * NODES + nl;

    float a0[8], a1[8], a2[8];
#pragma unroll
    for (int q = 0; q < 8; ++q) { a0[q] = 0.f; a1[q] = 0.f; a2[q] = 0.f; }

    const float4* x4 = (const float4*)xh;

    if (n < N) {
        int e0 = row_ptr[n], e1 = row_ptr[n + 1];
        int e = e0;
        for (; e + 16 <= e1; e += 16) {
            int cols[16];
            float2 gr[16];
#pragma unroll
            for (int j = 0; j < 16; ++j) cols[j] = col_idx[e + j];
#pragma unroll
            for (int j = 0; j < 16; ++j) gr[j] = gaussh[e + j];
            float4 xrA[8], xrB[8];
#pragma unroll
            for (int j = 0; j < 8; ++j) xrA[j] = x4[(size_t)cols[j] * TPN + ch];
#pragma unroll
            for (int j = 0; j < 8; ++j) xrB[j] = x4[(size_t)cols[8 + j] * TPN + ch];
#pragma unroll
            for (int j = 0; j < 8; ++j) fma_edge(xrA[j], gr[j], a0, a1, a2);
#pragma unroll
            for (int j = 0; j < 8; ++j) fma_edge(xrB[j], gr[8 + j], a0, a1, a2);
        }
        for (; e < e1; ++e) {
            int c = col_idx[e];
            fma_edge(x4[(size_t)c * TPN + ch], gaussh[e], a0, a1, a2);
        }
    }

    // dump s-tile to LDS (fp16)
    {
        union { __half h[8]; half8 v; } o;
#pragma unroll
        for (int q = 0; q < 8; ++q) o.h[q] = __float2half(a0[q]);
        *(half8*)(sLh + nl * STRIDE + 0 * F + ch * 8) = o.v;
#pragma unroll
        for (int q = 0; q < 8; ++q) o.h[q] = __float2half(a1[q]);
        *(half8*)(sLh + nl * STRIDE + 1 * F + ch * 8) = o.v;
#pragma unroll
        for (int q = 0; q < 8; ++q) o.h[q] = __float2half(a2[q]);
        *(half8*)(sLh + nl * STRIDE + 2 * F + ch * 8) = o.v;
    }
    __syncthreads();

    // phase 2: wave -> (node-tile, output-tile)
    {
        const int wv   = tid >> 6;
        const int lane = tid & 63;
        const int tile = wv / OT;
        const int ot   = wv % OT;
        const int n0   = blockIdx.x * NODES + tile * 16;
        if (n0 < N) {
            const int quad = lane >> 4;
            const int m    = lane & 15;

            half8 b[KB];
#pragma unroll
            for (int kb = 0; kb < KB; ++kb)
                b[kb] = ((const half8*)Bpack)[(ot * KB + kb) * 64 + lane];

            const half8* av = (const half8*)(sLh + (size_t)(tile * 16 + m) * STRIDE);
            float4v acc = {0.f, 0.f, 0.f, 0.f};
#pragma unroll
            for (int kb = 0; kb < KB; ++kb)
                acc = __builtin_amdgcn_mfma_f32_16x16x32_f16(av[kb * 4 + quad], b[kb], acc, 0, 0, 0);

            // C/D: col = lane&15 (output), row = quad*4+reg (node)
#pragma unroll
            for (int reg = 0; reg < 4; ++reg) {
                int nn = n0 + quad * 4 + reg;
                if (nn < N) {
                    if constexpr (OUT_HALF)
                        ((__half*)yout)[(size_t)nn * H + ot * 16 + m] = __float2half(acc[reg]);
                    else
                        ((float*)yout)[(size_t)nn * H + m] = acc[reg];
                }
            }
        }
    }
}

extern "C" void kernel_launch(void* const* d_in, const int* in_sizes, int n_in,
                              void* d_out, int out_size, void* d_ws, size_t ws_size,
                              hipStream_t stream) {
    const int* row_ptr  = (const int*)d_in[0];
    const int* col_idx  = (const int*)d_in[1];
    const float* x      = (const float*)d_in[2];
    const float* p      = (const float*)d_in[3];
    const float* mu     = (const float*)d_in[4];
    const float* sigma  = (const float*)d_in[5];
    const float* W1     = (const float*)d_in[6];
    const float* W2     = (const float*)d_in[7];

    const int N = in_sizes[0] - 1;
    const int E = in_sizes[1];

    float2* gaussh = (float2*)d_ws;                  // E * 8 B
    __half* B1pack = (__half*)(gaussh + (size_t)E);  // 6144 halves
    __half* B2pack = B1pack + 6144;                  // 1536 halves
    __half* xh     = B2pack + 1536;                  // N*64 fp16
    __half* hh     = xh + (size_t)N * 64;            // N*32 fp16
    float*  out    = (float*)d_out;                  // N*16 f32

    const int B = 256;
    const int NX8 = N * 8;
    int setup_n = E > NX8 ? E : NX8;
    if (setup_n < 7680) setup_n = 7680;

    setup_kernel<<<(setup_n + B - 1) / B, B, 0, stream>>>(
        p, mu, sigma, gaussh, x, xh, W1, W2, B1pack, B2pack, E, NX8);

    fused_layer<64, 32, true><<<(N + 31) / 32, B, 0, stream>>>(
        row_ptr, col_idx, gaussh, xh, B1pack, (void*)hh, N);
    fused_layer<32, 16, false><<<(N + 63) / 64, B, 0, stream>>>(
        row_ptr, col_idx, gaussh, hh, B2pack, (void*)out, N);
}